// Round 20
// baseline (2519.655 us; speedup 1.0000x reference)
//
#include <hip/hip_runtime.h>
#include <hip/hip_bf16.h>

#define B_   8
#define T_   512
#define S_   1024
#define D_   768
#define H_   12
#define DH_  64
#define L_   12
#define DFF_ 3072
#define M_   8192
#define QKVD 2304

typedef float f32x4 __attribute__((ext_vector_type(4)));
typedef short b16x8 __attribute__((ext_vector_type(8)));
typedef short s16x4 __attribute__((ext_vector_type(4)));

#define LDS_CAST(p) ((__attribute__((address_space(3))) void*)(unsigned)(unsigned long long)(p))
#define GBL_CAST(p) ((const __attribute__((address_space(1))) void*)(unsigned long long)(p))

__device__ inline short f2b(float f) {
  unsigned u = __builtin_bit_cast(unsigned, f);
  unsigned r = u + 0x7fffu + ((u >> 16) & 1u);
  return (short)(unsigned short)(r >> 16);
}
__device__ inline float b2f(short s) {
  unsigned u = ((unsigned)(unsigned short)s) << 16;
  return __builtin_bit_cast(float, u);
}
__device__ inline float gelu_f(float v) {
  const float e = __expf(v * (1.5957691216f + 0.0713548162f * v * v));
  return v * e / (e + 1.0f);
}
__device__ inline float tanh_f(float v) {
  const float e = __expf(2.0f * v);
  return 1.0f - 2.0f / (e + 1.0f);
}

// ---------------- fp32 -> bf16 elementwise (states)
__global__ __launch_bounds__(256) void cvt_kernel(const float* __restrict__ in,
                                                  short* __restrict__ out, int n) {
  const int i = (blockIdx.x * 256 + threadIdx.x) * 4;
  if (i < n) {
    const f32x4 v = *(const f32x4*)&in[i];
    out[i] = f2b(v.x); out[i + 1] = f2b(v.y); out[i + 2] = f2b(v.z); out[i + 3] = f2b(v.w);
  }
}

// ---------------- weight transpose + fp32->bf16 convert (embed path only)
__global__ __launch_bounds__(256) void trconv_kernel(const float* __restrict__ W,
                                                     short* __restrict__ Wt,
                                                     int K, int N) {
  __shared__ float tile[32][33];
  const int k0 = blockIdx.x * 32, n0 = blockIdx.y * 32;
  const int tx = threadIdx.x & 31, ty = threadIdx.x >> 5;
  #pragma unroll
  for (int i = ty; i < 32; i += 8) tile[i][tx] = W[(size_t)(k0 + i) * N + (n0 + tx)];
  __syncthreads();
  #pragma unroll
  for (int i = ty; i < 32; i += 8) Wt[(size_t)(n0 + i) * K + (k0 + tx)] = f2b(tile[tx][i]);
}

// all 6 per-layer weight transposes in ONE launch, 64(k)x32(n) tiles, s16x4 stores
__global__ __launch_bounds__(256) void trconv_layer(const float* __restrict__ Wq,
                                                    const float* __restrict__ Wk,
                                                    const float* __restrict__ Wv,
                                                    const float* __restrict__ Wp,
                                                    const float* __restrict__ W1,
                                                    const float* __restrict__ W2,
                                                    short* __restrict__ Dqkv,
                                                    short* __restrict__ Dp,
                                                    short* __restrict__ D1,
                                                    short* __restrict__ D2) {
  __shared__ float tile[64][33];
  int id = blockIdx.x;
  const float* W; short* Dst; int K, N, kt, nt;
  if (id < 1152) {
    const int wsel = id / 288; id -= wsel * 288;
    W   = (wsel == 0) ? Wq : (wsel == 1) ? Wk : (wsel == 2) ? Wv : Wp;
    Dst = (wsel == 3) ? Dp : (Dqkv + (size_t)wsel * D_ * D_);
    K = D_; N = D_; kt = id / 24; nt = id % 24;
  } else if (id < 2304) {
    id -= 1152; W = W1; Dst = D1; K = D_; N = DFF_; kt = id / 96; nt = id % 96;
  } else {
    id -= 2304; W = W2; Dst = D2; K = DFF_; N = D_; kt = id / 24; nt = id % 24;
  }
  const int k0 = kt * 64, n0 = nt * 32;
  const int tid = threadIdx.x;
  const int tx = tid & 31, ty = tid >> 5;
  #pragma unroll
  for (int i = ty; i < 64; i += 8) tile[i][tx] = W[(size_t)(k0 + i) * N + (n0 + tx)];
  __syncthreads();
  const int iq = tid >> 4, q = tid & 15;
  #pragma unroll
  for (int s = 0; s < 2; ++s) {
    const int n = iq + 16 * s;
    s16x4 o4;
    o4.x = f2b(tile[q * 4 + 0][n]);
    o4.y = f2b(tile[q * 4 + 1][n]);
    o4.z = f2b(tile[q * 4 + 2][n]);
    o4.w = f2b(tile[q * 4 + 3][n]);
    *(s16x4*)&Dst[(size_t)(n0 + n) * K + k0 + q * 4] = o4;
  }
}

// ---------------- token combine: x(bf16) = se / tanh(A_emb[a]) + gpos + pos
__global__ __launch_bounds__(256) void embed2_kernel(
    const short* __restrict__ se, const int* __restrict__ actions,
    const int* __restrict__ timesteps, const float* __restrict__ A_emb,
    const float* __restrict__ pos_emb, const float* __restrict__ gpos_emb,
    short* __restrict__ x) {
  const int bt = blockIdx.x;
  const int b = bt >> 9, t = bt & 511;
  const int tid = threadIdx.x;
  const int act = actions[bt];
  const int ts = timesteps[b];
  const float* gp = gpos_emb + (size_t)ts * D_;
  #pragma unroll
  for (int i = 0; i < 3; ++i) {
    const int d = tid + i * 256;
    const float sev = b2f(se[(size_t)bt * D_ + d]);
    const float aev = tanhf(A_emb[act * D_ + d]);
    const float g = gp[d];
    const size_t base = ((size_t)b * S_ + 2 * t) * D_ + d;
    x[base]      = f2b(sev + g + pos_emb[(2 * t) * D_ + d]);
    x[base + D_] = f2b(aev + g + pos_emb[(2 * t + 1) * D_ + d]);
  }
}

// ---------------- layernorm, 4 rows/block (768 thr, all waves active)
__global__ __launch_bounds__(768) void ln_kernel(const short* __restrict__ x,
                                                 const float* __restrict__ gg,
                                                 const float* __restrict__ bb,
                                                 short* __restrict__ out) {
  __shared__ float red[12];
  const int tid = threadIdx.x;
  const int row = blockIdx.x * 4 + (tid / 192);
  const int t = tid % 192;
  const int wave = tid >> 6;          // 0..11, 3 waves per row
  const int r3 = (tid / 192) * 3;
  const short* xr = x + (size_t)row * D_;
  const s16x4 xv = *(const s16x4*)&xr[t * 4];
  f32x4 v = {b2f(xv.x), b2f(xv.y), b2f(xv.z), b2f(xv.w)};
  float s = v.x + v.y + v.z + v.w;
  #pragma unroll
  for (int o = 32; o > 0; o >>= 1) s += __shfl_xor(s, o);
  if ((tid & 63) == 0) red[wave] = s;
  __syncthreads();
  const float mean = (red[r3] + red[r3 + 1] + red[r3 + 2]) * (1.0f / D_);
  __syncthreads();
  const f32x4 d = {v.x - mean, v.y - mean, v.z - mean, v.w - mean};
  float s2 = d.x * d.x + d.y * d.y + d.z * d.z + d.w * d.w;
  #pragma unroll
  for (int o = 32; o > 0; o >>= 1) s2 += __shfl_xor(s2, o);
  if ((tid & 63) == 0) red[wave] = s2;
  __syncthreads();
  const float inv = rsqrtf((red[r3] + red[r3 + 1] + red[r3 + 2]) * (1.0f / D_) + 1e-5f);
  const f32x4 g = *(const f32x4*)&gg[t * 4];
  const f32x4 b = *(const f32x4*)&bb[t * 4];
  s16x4 o4;
  o4.x = f2b(d.x * inv * g.x + b.x);
  o4.y = f2b(d.y * inv * g.y + b.y);
  o4.z = f2b(d.z * inv * g.z + b.z);
  o4.w = f2b(d.w * inv * g.w + b.w);
  *(s16x4*)&out[(size_t)row * D_ + t * 4] = o4;
}

// ---------------- split-K2 reduce + bias + residual + LN, 4 rows/block
// MODE 1: rows = blockIdx*4+sub; x += P0+P1+bias (bf16 RMW); h = LN(x')
// MODE 2: rows = (blockIdx*4+sub)*2 (even rows); out = LN(...) fp32
template <int MODE>
__global__ __launch_bounds__(768) void reduce2_kernel(
    const short* __restrict__ P, const float* __restrict__ bias,
    short* __restrict__ x, const float* __restrict__ gg,
    const float* __restrict__ bb, short* __restrict__ h,
    float* __restrict__ out) {
  __shared__ float red[12];
  const int tid = threadIdx.x;
  const int sub = tid / 192;
  const int row = (MODE == 2) ? ((blockIdx.x * 4 + sub) * 2) : (blockIdx.x * 4 + sub);
  const int t = tid % 192;
  const int wave = tid >> 6;
  const int r3 = sub * 3;
  const short* p0 = P + (size_t)row * D_;
  const short* p1 = P + (size_t)M_ * D_ + (size_t)row * D_;
  short* xr = x + (size_t)row * D_;
  const s16x4 a = *(const s16x4*)&xr[t * 4];
  const s16x4 q0 = *(const s16x4*)&p0[t * 4];
  const s16x4 q1 = *(const s16x4*)&p1[t * 4];
  const f32x4 bv = *(const f32x4*)&bias[t * 4];
  f32x4 v;
  v.x = b2f(a.x) + b2f(q0.x) + b2f(q1.x) + bv.x;
  v.y = b2f(a.y) + b2f(q0.y) + b2f(q1.y) + bv.y;
  v.z = b2f(a.z) + b2f(q0.z) + b2f(q1.z) + bv.z;
  v.w = b2f(a.w) + b2f(q0.w) + b2f(q1.w) + bv.w;
  if (MODE == 1) {
    s16x4 xo;
    xo.x = f2b(v.x); xo.y = f2b(v.y); xo.z = f2b(v.z); xo.w = f2b(v.w);
    *(s16x4*)&xr[t * 4] = xo;
  }
  float s = v.x + v.y + v.z + v.w;
  #pragma unroll
  for (int o = 32; o > 0; o >>= 1) s += __shfl_xor(s, o);
  if ((tid & 63) == 0) red[wave] = s;
  __syncthreads();
  const float mean = (red[r3] + red[r3 + 1] + red[r3 + 2]) * (1.0f / D_);
  __syncthreads();
  const f32x4 d = {v.x - mean, v.y - mean, v.z - mean, v.w - mean};
  float s2 = d.x * d.x + d.y * d.y + d.z * d.z + d.w * d.w;
  #pragma unroll
  for (int o = 32; o > 0; o >>= 1) s2 += __shfl_xor(s2, o);
  if ((tid & 63) == 0) red[wave] = s2;
  __syncthreads();
  const float inv = rsqrtf((red[r3] + red[r3 + 1] + red[r3 + 2]) * (1.0f / D_) + 1e-5f);
  const f32x4 g = *(const f32x4*)&gg[t * 4];
  const f32x4 b = *(const f32x4*)&bb[t * 4];
  if (MODE == 1) {
    s16x4 o4;
    o4.x = f2b(d.x * inv * g.x + b.x);
    o4.y = f2b(d.y * inv * g.y + b.y);
    o4.z = f2b(d.z * inv * g.z + b.z);
    o4.w = f2b(d.w * inv * g.w + b.w);
    *(s16x4*)&h[(size_t)row * D_ + t * 4] = o4;
  } else {
    const int bb2 = row >> 10, tt = (row & 1023) >> 1;
    f32x4 o4;
    o4.x = d.x * inv * g.x + b.x;
    o4.y = d.y * inv * g.y + b.y;
    o4.z = d.z * inv * g.z + b.z;
    o4.w = d.w * inv * g.w + b.w;
    *(f32x4*)&out[((size_t)bb2 * T_ + tt) * D_ + t * 4] = o4;
  }
}

// ---------------- 128x128 main loop, BK=64, chunk-XOR swizzle (embed GEMM)
__device__ __forceinline__ void mainloop128(const short* __restrict__ gA,
                                            const short* __restrict__ gB,
                                            int K, int kIters,
                                            short* As, short* Bs,
                                            int wave, int l15, int lq, int wr, int wc,
                                            f32x4 (&acc)[4][4]) {
  auto STAGE = [&](int kt, int buf) {
    const short* a = gA + kt * 64;
    const short* b = gB + kt * 64;
    short* la = As + buf * 8192 + wave * 512;
    short* lb = Bs + buf * 8192 + wave * 512;
    #pragma unroll
    for (int j = 0; j < 4; ++j) {
      __builtin_amdgcn_global_load_lds(GBL_CAST(a + (size_t)(j * 32) * K), LDS_CAST(la + j * 2048), 16, 0, 0);
      __builtin_amdgcn_global_load_lds(GBL_CAST(b + (size_t)(j * 32) * K), LDS_CAST(lb + j * 2048), 16, 0, 0);
    }
  };
  STAGE(0, 0);
  __syncthreads();
  int cur = 0;
  const int swz = l15 & 7;
  for (int kt = 0; kt < kIters; ++kt) {
    if (kt + 1 < kIters) STAGE(kt + 1, cur ^ 1);
    const short* Ab = As + cur * 8192;
    const short* Bb = Bs + cur * 8192;
    #pragma unroll
    for (int s = 0; s < 2; ++s) {
      const int ck = ((s * 4 + lq) ^ swz) * 8;
      b16x8 af[4], bfr[4];
      #pragma unroll
      for (int i = 0; i < 4; ++i)
        af[i] = *(const b16x8*)&Ab[(wr * 64 + i * 16 + l15) * 64 + ck];
      #pragma unroll
      for (int j = 0; j < 4; ++j)
        bfr[j] = *(const b16x8*)&Bb[(wc * 64 + j * 16 + l15) * 64 + ck];
      __builtin_amdgcn_s_setprio(1);
      #pragma unroll
      for (int i = 0; i < 4; ++i)
        #pragma unroll
        for (int j = 0; j < 4; ++j)
          acc[i][j] = __builtin_amdgcn_mfma_f32_16x16x32_bf16(af[i], bfr[j], acc[i][j], 0, 0, 0);
      __builtin_amdgcn_s_setprio(0);
    }
    __syncthreads();
    cur ^= 1;
  }
}

// ---------------- GEMM 128x128 (embed path): EPI 4: tanh->bf16
template <int EPI>
__global__ __launch_bounds__(256) void gemm_bf16(const short* __restrict__ A,
                                                 const short* __restrict__ Bt,
                                                 const float* __restrict__ bias,
                                                 short* __restrict__ Cb,
                                                 int M, int N, int K) {
  __shared__ __align__(16) short As[16384];
  __shared__ __align__(16) short Bs[16384];
  const int tid = threadIdx.x;
  const int wave = tid >> 6, lane = tid & 63;
  const int l15 = lane & 15, lq = lane >> 4;
  const int wr = wave >> 1, wc = wave & 1;
  const int row0 = blockIdx.x * 128, col0 = blockIdx.y * 128;
  const int srow = wave * 8 + (lane >> 3);
  const int acs = ((lane & 7) ^ ((lane >> 3) & 7)) * 8;

  const short* gA = A + (size_t)(row0 + srow) * K + acs;
  const short* gB = Bt + (size_t)(col0 + srow) * K + acs;
  f32x4 acc[4][4] = {};
  mainloop128(gA, gB, K, K / 64, As, Bs, wave, l15, lq, wr, wc, acc);

  #pragma unroll
  for (int i = 0; i < 4; ++i) {
    #pragma unroll
    for (int j = 0; j < 4; ++j) {
      const int col = col0 + wc * 64 + j * 16 + l15;
      const float bv = bias[col];
      #pragma unroll
      for (int r = 0; r < 4; ++r) {
        const int row = row0 + wr * 64 + i * 16 + lq * 4 + r;
        const float v = acc[i][j][r] + bv;
        const size_t idx = (size_t)row * N + col;
        if (EPI == 1) Cb[idx] = f2b(gelu_f(v));
        else          Cb[idx] = f2b(tanh_f(v));
      }
    }
  }
}

// ================ 192-wide GEMM, BM x 192 tile, BK=64, chunk-XOR swizzle
// EPI 1: gelu->bf16 (Cb); EPI 2: bf16 partial (Cb + z*M*N); EPI 3: bf16 residual += (Xres)
template <int BM, int EPI>
__global__ __launch_bounds__(256) void gemm192(const short* __restrict__ A,
                                               const short* __restrict__ Bt,
                                               const float* __restrict__ bias,
                                               short* __restrict__ Cb,
                                               short* __restrict__ Xres,
                                               int M, int N, int K, int KC) {
  constexpr int AHALF = BM * 64;
  __shared__ __align__(16) short As[2 * AHALF];
  __shared__ __align__(16) short Bs[24576];
  const int tid = threadIdx.x;
  const int wave = tid >> 6, lane = tid & 63;
  const int l15 = lane & 15, lq = lane >> 4;
  const int wr = wave >> 1, wc = wave & 1;
  const int row0 = blockIdx.x * BM, col0 = blockIdx.y * 192;
  const int k0 = blockIdx.z * KC;
  const int srow = wave * 8 + (lane >> 3);
  const int acs = ((lane & 7) ^ ((lane >> 3) & 7)) * 8;

  const short* gA = A + (size_t)(row0 + srow) * K + acs + k0;
  const short* gB = Bt + (size_t)(col0 + srow) * K + acs + k0;

  auto STAGE = [&](int kt, int buf) {
    const short* a = gA + kt * 64;
    const short* b = gB + kt * 64;
    short* la = As + buf * AHALF + wave * 512;
    short* lb = Bs + buf * 12288 + wave * 512;
    #pragma unroll
    for (int j = 0; j < BM / 32; ++j)
      __builtin_amdgcn_global_load_lds(GBL_CAST(a + (size_t)(j * 32) * K), LDS_CAST(la + j * 2048), 16, 0, 0);
    #pragma unroll
    for (int j = 0; j < 6; ++j)
      __builtin_amdgcn_global_load_lds(GBL_CAST(b + (size_t)(j * 32) * K), LDS_CAST(lb + j * 2048), 16, 0, 0);
  };

  constexpr int MI = BM / 32;
  f32x4 acc[MI][6] = {};
  const int kIters = KC / 64;
  STAGE(0, 0);
  __syncthreads();
  int cur = 0;
  const int swz = l15 & 7;
  for (int kt = 0; kt < kIters; ++kt) {
    if (kt + 1 < kIters) STAGE(kt + 1, cur ^ 1);
    const short* Ab = As + cur * AHALF;
    const short* Bb = Bs + cur * 12288;
    #pragma unroll
    for (int s = 0; s < 2; ++s) {
      const int ck = ((s * 4 + lq) ^ swz) * 8;
      b16x8 af[MI], bfr[6];
      #pragma unroll
      for (int i = 0; i < MI; ++i)
        af[i] = *(const b16x8*)&Ab[(wr * (BM / 2) + i * 16 + l15) * 64 + ck];
      #pragma unroll
      for (int j = 0; j < 6; ++j)
        bfr[j] = *(const b16x8*)&Bb[(wc * 96 + j * 16 + l15) * 64 + ck];
      __builtin_amdgcn_s_setprio(1);
      #pragma unroll
      for (int i = 0; i < MI; ++i)
        #pragma unroll
        for (int j = 0; j < 6; ++j)
          acc[i][j] = __builtin_amdgcn_mfma_f32_16x16x32_bf16(af[i], bfr[j], acc[i][j], 0, 0, 0);
      __builtin_amdgcn_s_setprio(0);
    }
    __syncthreads();
    cur ^= 1;
  }

  #pragma unroll
  for (int i = 0; i < MI; ++i) {
    #pragma unroll
    for (int j = 0; j < 6; ++j) {
      const int col = col0 + wc * 96 + j * 16 + l15;
      #pragma unroll
      for (int r = 0; r < 4; ++r) {
        const int row = row0 + wr * (BM / 2) + i * 16 + lq * 4 + r;
        if (EPI == 1) {
          Cb[(size_t)row * N + col] = f2b(gelu_f(acc[i][j][r] + bias[col]));
        } else if (EPI == 2) {
          (Cb + (size_t)blockIdx.z * M * N)[(size_t)row * N + col] = f2b(acc[i][j][r]);
        } else {
          short* xp = &Xres[(size_t)row * N + col];
          *xp = f2b(b2f(*xp) + acc[i][j][r] + bias[col]);
        }
      }
    }
  }
}

// ---------------- fused QKV GEMM, 128x192 tile, BK=64 (R15-verified)
__global__ __launch_bounds__(256) void gemm_qkv(const short* __restrict__ A,
                                                const short* __restrict__ Bt,
                                                const float* __restrict__ bq,
                                                const float* __restrict__ bk,
                                                const float* __restrict__ bv,
                                                short* __restrict__ Cb, int K) {
  __shared__ __align__(16) short As[16384];
  __shared__ __align__(16) short Bs[24576];
  const int tid = threadIdx.x;
  const int wave = tid >> 6, lane = tid & 63;
  const int l15 = lane & 15, lq = lane >> 4;
  const int wr = wave >> 1, wc = wave & 1;
  const int row0 = blockIdx.x * 128, col0 = blockIdx.y * 192;
  const int seg = col0 / D_;
  const float* bias = (seg == 0) ? bq : (seg == 1) ? bk : bv;
  const float scale = (seg == 0) ? 0.125f : 1.0f;
  const int srow = wave * 8 + (lane >> 3);
  const int acs = ((lane & 7) ^ ((lane >> 3) & 7)) * 8;

  const short* gA = A + (size_t)(row0 + srow) * K + acs;
  const short* gB = Bt + (size_t)(col0 + srow) * K + acs;

  auto STAGE = [&](int kt, int buf) {
    const short* a = gA + kt * 64;
    const short* b = gB + kt * 64;
    short* la = As + buf * 8192 + wave * 512;
    short* lb = Bs + buf * 12288 + wave * 512;
    #pragma unroll
    for (int j = 0; j < 4; ++j)
      __builtin_amdgcn_global_load_lds(GBL_CAST(a + (size_t)(j * 32) * K), LDS_CAST(la + j * 2048), 16, 0, 0);
    #pragma unroll
    for (int j = 0; j < 6; ++j)
      __builtin_amdgcn_global_load_lds(GBL_CAST(b + (size_t)(j * 32) * K), LDS_CAST(lb + j * 2048), 16, 0, 0);
  };

  f32x4 acc[4][6] = {};
  const int kIters = K / 64;
  STAGE(0, 0);
  __syncthreads();
  int cur = 0;
  const int swz = l15 & 7;
  for (int kt = 0; kt < kIters; ++kt) {
    if (kt + 1 < kIters) STAGE(kt + 1, cur ^ 1);
    const short* Ab = As + cur * 8192;
    const short* Bb = Bs + cur * 12288;
    #pragma unroll
    for (int s = 0; s < 2; ++s) {
      const int ck = ((s * 4 + lq) ^ swz) * 8;
      b16x8 af[4], bfr[6];
      #pragma unroll
      for (int i = 0; i < 4; ++i)
        af[i] = *(const b16x8*)&Ab[(wr * 64 + i * 16 + l15) * 64 + ck];
      #pragma unroll
      for (int j = 0; j < 6; ++j)
        bfr[j] = *(const b16x8*)&Bb[(wc * 96 + j * 16 + l15) * 64 + ck];
      __builtin_amdgcn_s_setprio(1);
      #pragma unroll
      for (int i = 0; i < 4; ++i)
        #pragma unroll
        for (int j = 0; j < 6; ++j)
          acc[i][j] = __builtin_amdgcn_mfma_f32_16x16x32_bf16(af[i], bfr[j], acc[i][j], 0, 0, 0);
      __builtin_amdgcn_s_setprio(0);
    }
    __syncthreads();
    cur ^= 1;
  }

  #pragma unroll
  for (int i = 0; i < 4; ++i) {
    #pragma unroll
    for (int j = 0; j < 6; ++j) {
      const int col = col0 + wc * 96 + j * 16 + l15;
      const float bv = bias[col - seg * D_];
      #pragma unroll
      for (int r = 0; r < 4; ++r) {
        const int row = row0 + wr * 64 + i * 16 + lq * 4 + r;
        Cb[(size_t)row * QKVD + col] = f2b((acc[i][j][r] + bv) * scale);
      }
    }
  }
}

// ---------------- flash attention, balanced pairing, FIXED-MAX softmax, T14 split
__global__ __launch_bounds__(256) void attn_kernel(const short* __restrict__ qkv,
                                                   short* __restrict__ yb) {
  __shared__ __align__(16) short Ks[2][4096];
  __shared__ __align__(16) short Vt[2][64 * 72];
  __shared__ __align__(16) short Ps[4][16 * 88];

  const int bh = blockIdx.x, pair = blockIdx.y;
  const int h = bh % H_, b = bh / H_;
  const int tid = threadIdx.x, wave = tid >> 6, lane = tid & 63;
  const int l15 = lane & 15, lq = lane >> 4;

  const int r0 = tid >> 3, c0 = tid & 7;
  const int r1 = (tid + 256) >> 3;
  const int vkey = tid >> 2, vdhg = tid & 3;

  for (int t2 = 0; t2 < 2; ++t2) {
    const int qt = t2 ? (15 - pair) : pair;
    const int nkt = qt + 1;
    const int qrow0 = qt * 64 + wave * 16;

    const short* qp = qkv + (size_t)(b * S_ + qrow0 + l15) * QKVD + h * 64 + lq * 8;
    const b16x8 qf0 = *(const b16x8*)qp;
    const b16x8 qf1 = *(const b16x8*)(qp + 32);

    f32x4 o[4] = {};
    float lacc[4] = {0.f, 0.f, 0.f, 0.f};

    auto issueK = [&](int kt, int s) {
      const int kbase = kt * 64;
      const short* gk0 = qkv + (size_t)(b * S_ + kbase + r0) * QKVD + D_ + h * 64 + ((c0 ^ (r0 & 7)) * 8);
      __builtin_amdgcn_global_load_lds(GBL_CAST(gk0), LDS_CAST(&Ks[s][wave * 512]), 16, 0, 0);
      const short* gk1 = qkv + (size_t)(b * S_ + kbase + r1) * QKVD + D_ + h * 64 + ((c0 ^ (r1 & 7)) * 8);
      __builtin_amdgcn_global_load_lds(GBL_CAST(gk1), LDS_CAST(&Ks[s][2048 + wave * 512]), 16, 0, 0);
    };
    auto loadV = [&](int kt, b16x8& v0, b16x8& v1) {
      const short* gv = qkv + (size_t)(b * S_ + kt * 64 + vkey) * QKVD + 2 * D_ + h * 64 + vdhg * 16;
      v0 = *(const b16x8*)gv;
      v1 = *(const b16x8*)(gv + 8);
    };
    auto writeV = [&](int s, const b16x8& v0, const b16x8& v1) {
      #pragma unroll
      for (int e = 0; e < 8; ++e) Vt[s][(vdhg * 16 + e) * 72 + vkey] = v0[e];
      #pragma unroll
      for (int e = 0; e < 8; ++e) Vt[s][(vdhg * 16 + 8 + e) * 72 + vkey] = v1[e];
    };

    {
      b16x8 pv0, pv1;
      issueK(0, 0);
      loadV(0, pv0, pv1);
      writeV(0, pv0, pv1);
    }
    __syncthreads();

    for (int kt = 0; kt < nkt; ++kt) {
      const int cur = kt & 1;
      const bool have_next = (kt + 1 < nkt);
      b16x8 nv0, nv1;
      if (have_next) {
        issueK(kt + 1, cur ^ 1);
        loadV(kt + 1, nv0, nv1);
      }
      const int kbase = kt * 64;
      const bool needmask = (kt == qt);

      f32x4 s4[4];
      #pragma unroll
      for (int j = 0; j < 4; ++j) {
        const int krow = j * 16 + l15;
        const b16x8 kf0 = *(const b16x8*)&Ks[cur][krow * 64 + ((lq ^ (krow & 7)) * 8)];
        const b16x8 kf1 = *(const b16x8*)&Ks[cur][krow * 64 + (((4 + lq) ^ (krow & 7)) * 8)];
        f32x4 z = {};
        z = __builtin_amdgcn_mfma_f32_16x16x32_bf16(qf0, kf0, z, 0, 0, 0);
        s4[j] = __builtin_amdgcn_mfma_f32_16x16x32_bf16(qf1, kf1, z, 0, 0, 0);
      }

      #pragma unroll
      for (int r = 0; r < 4; ++r) {
        const int q = qrow0 + lq * 4 + r;
        float psum = 0.f;
        #pragma unroll
        for (int j = 0; j < 4; ++j) {
          float pp = __expf(s4[j][r]);
          if (needmask && (kbase + j * 16 + l15 > q)) pp = 0.f;
          psum += pp;
          Ps[wave][(lq * 4 + r) * 88 + j * 16 + l15] = f2b(pp);
        }
        lacc[r] += psum;
      }

      if (have_next) writeV(cur ^ 1, nv0, nv1);

      #pragma unroll
      for (int c = 0; c < 2; ++c) {
        const b16x8 pf = *(const b16x8*)&Ps[wave][l15 * 88 + c * 32 + lq * 8];
        #pragma unroll
        for (int jn = 0; jn < 4; ++jn) {
          const b16x8 vf = *(const b16x8*)&Vt[cur][(jn * 16 + l15) * 72 + c * 32 + lq * 8];
          o[jn] = __builtin_amdgcn_mfma_f32_16x16x32_bf16(pf, vf, o[jn], 0, 0, 0);
        }
      }
      __syncthreads();
    }

    #pragma unroll
    for (int r = 0; r < 4; ++r) {
      #pragma unroll
      for (int ofs = 1; ofs < 16; ofs <<= 1) lacc[r] += __shfl_xor(lacc[r], ofs);
      lacc[r] = 1.0f / lacc[r];
    }

    #pragma unroll
    for (int jn = 0; jn < 4; ++jn) {
      #pragma unroll
      for (int r = 0; r < 4; ++r) {
        const int q = qrow0 + lq * 4 + r;
        const int dh = jn * 16 + l15;
        yb[(size_t)(b * S_ + q) * D_ + h * 64 + dh] = f2b(o[jn][r] * lacc[r]);
      }
    }
  }
}

// ---------------- host-side orchestration
extern "C" void kernel_launch(void* const* d_in, const int* in_sizes, int n_in,
                              void* d_out, int out_size, void* d_ws, size_t ws_size,
                              hipStream_t stream) {
  (void)in_sizes; (void)n_in; (void)out_size; (void)ws_size;
  const float* states    = (const float*)d_in[0];
  const int*   actions   = (const int*)d_in[1];
  const int*   timesteps = (const int*)d_in[2];
  const float* W_s       = (const float*)d_in[3];
  const float* b_s       = (const float*)d_in[4];
  const float* A_emb     = (const float*)d_in[5];
  const float* pos_emb   = (const float*)d_in[6];
  const float* gpos_emb  = (const float*)d_in[7];
  const float* ln1_g     = (const float*)d_in[8];
  const float* ln1_b     = (const float*)d_in[9];
  const float* Wq        = (const float*)d_in[10];
  const float* bq        = (const float*)d_in[11];
  const float* Wk        = (const float*)d_in[12];
  const float* bk        = (const float*)d_in[13];
  const float* Wv        = (const float*)d_in[14];
  const float* bv        = (const float*)d_in[15];
  const float* Wp        = (const float*)d_in[16];
  const float* bp        = (const float*)d_in[17];
  const float* ln2_g     = (const float*)d_in[18];
  const float* ln2_b     = (const float*)d_in[19];
  const float* W1        = (const float*)d_in[20];
  const float* b1        = (const float*)d_in[21];
  const float* W2        = (const float*)d_in[22];
  const float* b2        = (const float*)d_in[23];
  const float* lnf_g     = (const float*)d_in[24];
  const float* lnf_b     = (const float*)d_in[25];
  float* out = (float*)d_out;

  char* p = (char*)d_ws;
  short* x    = (short*)p; p += (size_t)M_ * D_ * 2;
  short* h    = (short*)p; p += (size_t)M_ * D_ * 2;
  short* qkv  = (short*)p; p += (size_t)M_ * QKVD * 2;
  short* y    = (short*)p; p += (size_t)M_ * D_ * 2;
  short* gbf  = (short*)p; p += (size_t)M_ * DFF_ * 2;
  short* wqkvt= (short*)p; p += (size_t)QKVD * D_ * 2;
  short* wpt  = (short*)p; p += (size_t)D_ * D_ * 2;
  short* w1t  = (short*)p; p += (size_t)D_ * DFF_ * 2;
  short* w2t  = (short*)p; p += (size_t)D_ * DFF_ * 2;
  // split-K bf16 partial buffer [2][M][D] aliases qkv+y (dead when FFN2 runs)
  short* Pbuf = qkv;
  // transient (pre-layer) aliases
  short* sbf  = qkv;                       // [4096][128] bf16
  short* wst  = qkv + (size_t)4096 * 128;  // [768][128] bf16
  short* se   = gbf;                       // [4096][768] bf16

  // ---- embedding path
  cvt_kernel<<<(B_ * T_ * 128) / 1024, 256, 0, stream>>>(states, sbf, B_ * T_ * 128);
  trconv_kernel<<<dim3(4, 24), 256, 0, stream>>>(W_s, wst, 128, D_);
  gemm_bf16<4><<<dim3(32, 6), 256, 0, stream>>>(sbf, wst, b_s, se, 4096, D_, 128);
  embed2_kernel<<<B_ * T_, 256, 0, stream>>>(se, actions, timesteps, A_emb, pos_emb, gpos_emb, x);
  ln_kernel<<<M_ / 4, 768, 0, stream>>>(x, ln1_g, ln1_b, h);

  for (int l = 0; l < L_; ++l) {
    trconv_layer<<<3456, 256, 0, stream>>>(
        Wq + (size_t)l * D_ * D_, Wk + (size_t)l * D_ * D_,
        Wv + (size_t)l * D_ * D_, Wp + (size_t)l * D_ * D_,
        W1 + (size_t)l * D_ * DFF_, W2 + (size_t)l * D_ * DFF_,
        wqkvt, wpt, w1t, w2t);

    gemm_qkv<<<dim3(M_ / 128, QKVD / 192), 256, 0, stream>>>(h, wqkvt, bq + l * D_, bk + l * D_, bv + l * D_, qkv, D_);
    attn_kernel<<<dim3(B_ * H_, 8), 256, 0, stream>>>(qkv, y);
    gemm192<64, 3><<<dim3(M_ / 64, D_ / 192), 256, 0, stream>>>(
        y, wpt, bp + l * D_, nullptr, x, M_, D_, D_, D_);
    ln_kernel<<<M_ / 4, 768, 0, stream>>>(x, ln2_g + l * D_, ln2_b + l * D_, h);
    gemm192<128, 1><<<dim3(M_ / 128, DFF_ / 192), 256, 0, stream>>>(
        h, w1t, b1 + l * DFF_, gbf, nullptr, M_, DFF_, D_, D_);
    gemm192<128, 2><<<dim3(M_ / 128, D_ / 192, 2), 256, 0, stream>>>(
        gbf, w2t, nullptr, Pbuf, nullptr, M_, D_, DFF_, DFF_ / 2);
    if (l < L_ - 1) {
      reduce2_kernel<1><<<M_ / 4, 768, 0, stream>>>(Pbuf, b2 + l * D_, x,
                                                    ln1_g + (l + 1) * D_, ln1_b + (l + 1) * D_, h, nullptr);
    } else {
      reduce2_kernel<2><<<M_ / 8, 768, 0, stream>>>(Pbuf, b2 + l * D_, x, lnf_g, lnf_b, nullptr, out);
    }
  }
}

// Round 21
// 2510.648 us; speedup vs baseline: 1.0036x; 1.0036x over previous
//
#include <hip/hip_runtime.h>
#include <hip/hip_bf16.h>

#define B_   8
#define T_   512
#define S_   1024
#define D_   768
#define H_   12
#define DH_  64
#define L_   12
#define DFF_ 3072
#define M_   8192
#define QKVD 2304

typedef float f32x4 __attribute__((ext_vector_type(4)));
typedef short b16x8 __attribute__((ext_vector_type(8)));
typedef short s16x4 __attribute__((ext_vector_type(4)));

#define LDS_CAST(p) ((__attribute__((address_space(3))) void*)(unsigned)(unsigned long long)(p))
#define GBL_CAST(p) ((const __attribute__((address_space(1))) void*)(unsigned long long)(p))

__device__ inline short f2b(float f) {
  unsigned u = __builtin_bit_cast(unsigned, f);
  unsigned r = u + 0x7fffu + ((u >> 16) & 1u);
  return (short)(unsigned short)(r >> 16);
}
__device__ inline float b2f(short s) {
  unsigned u = ((unsigned)(unsigned short)s) << 16;
  return __builtin_bit_cast(float, u);
}
__device__ inline float gelu_f(float v) {
  const float e = __expf(v * (1.5957691216f + 0.0713548162f * v * v));
  return v * e / (e + 1.0f);
}
__device__ inline float tanh_f(float v) {
  const float e = __expf(2.0f * v);
  return 1.0f - 2.0f / (e + 1.0f);
}

// ---------------- fp32 -> bf16 elementwise (states)
__global__ __launch_bounds__(256) void cvt_kernel(const float* __restrict__ in,
                                                  short* __restrict__ out, int n) {
  const int i = (blockIdx.x * 256 + threadIdx.x) * 4;
  if (i < n) {
    const f32x4 v = *(const f32x4*)&in[i];
    out[i] = f2b(v.x); out[i + 1] = f2b(v.y); out[i + 2] = f2b(v.z); out[i + 3] = f2b(v.w);
  }
}

// ---------------- weight transpose + fp32->bf16 convert (embed path only)
__global__ __launch_bounds__(256) void trconv_kernel(const float* __restrict__ W,
                                                     short* __restrict__ Wt,
                                                     int K, int N) {
  __shared__ float tile[32][33];
  const int k0 = blockIdx.x * 32, n0 = blockIdx.y * 32;
  const int tx = threadIdx.x & 31, ty = threadIdx.x >> 5;
  #pragma unroll
  for (int i = ty; i < 32; i += 8) tile[i][tx] = W[(size_t)(k0 + i) * N + (n0 + tx)];
  __syncthreads();
  #pragma unroll
  for (int i = ty; i < 32; i += 8) Wt[(size_t)(n0 + i) * K + (k0 + tx)] = f2b(tile[tx][i]);
}

// all 6 per-layer weight transposes in ONE launch, 64(k)x32(n) tiles, s16x4 stores
__global__ __launch_bounds__(256) void trconv_layer(const float* __restrict__ Wq,
                                                    const float* __restrict__ Wk,
                                                    const float* __restrict__ Wv,
                                                    const float* __restrict__ Wp,
                                                    const float* __restrict__ W1,
                                                    const float* __restrict__ W2,
                                                    short* __restrict__ Dqkv,
                                                    short* __restrict__ Dp,
                                                    short* __restrict__ D1,
                                                    short* __restrict__ D2) {
  __shared__ float tile[64][33];
  int id = blockIdx.x;
  const float* W; short* Dst; int K, N, kt, nt;
  if (id < 1152) {
    const int wsel = id / 288; id -= wsel * 288;
    W   = (wsel == 0) ? Wq : (wsel == 1) ? Wk : (wsel == 2) ? Wv : Wp;
    Dst = (wsel == 3) ? Dp : (Dqkv + (size_t)wsel * D_ * D_);
    K = D_; N = D_; kt = id / 24; nt = id % 24;
  } else if (id < 2304) {
    id -= 1152; W = W1; Dst = D1; K = D_; N = DFF_; kt = id / 96; nt = id % 96;
  } else {
    id -= 2304; W = W2; Dst = D2; K = DFF_; N = D_; kt = id / 24; nt = id % 24;
  }
  const int k0 = kt * 64, n0 = nt * 32;
  const int tid = threadIdx.x;
  const int tx = tid & 31, ty = tid >> 5;
  #pragma unroll
  for (int i = ty; i < 64; i += 8) tile[i][tx] = W[(size_t)(k0 + i) * N + (n0 + tx)];
  __syncthreads();
  const int iq = tid >> 4, q = tid & 15;
  #pragma unroll
  for (int s = 0; s < 2; ++s) {
    const int n = iq + 16 * s;
    s16x4 o4;
    o4.x = f2b(tile[q * 4 + 0][n]);
    o4.y = f2b(tile[q * 4 + 1][n]);
    o4.z = f2b(tile[q * 4 + 2][n]);
    o4.w = f2b(tile[q * 4 + 3][n]);
    *(s16x4*)&Dst[(size_t)(n0 + n) * K + k0 + q * 4] = o4;
  }
}

// ---------------- token combine: x(bf16) = se / tanh(A_emb[a]) + gpos + pos
__global__ __launch_bounds__(256) void embed2_kernel(
    const short* __restrict__ se, const int* __restrict__ actions,
    const int* __restrict__ timesteps, const float* __restrict__ A_emb,
    const float* __restrict__ pos_emb, const float* __restrict__ gpos_emb,
    short* __restrict__ x) {
  const int bt = blockIdx.x;
  const int b = bt >> 9, t = bt & 511;
  const int tid = threadIdx.x;
  const int act = actions[bt];
  const int ts = timesteps[b];
  const float* gp = gpos_emb + (size_t)ts * D_;
  #pragma unroll
  for (int i = 0; i < 3; ++i) {
    const int d = tid + i * 256;
    const float sev = b2f(se[(size_t)bt * D_ + d]);
    const float aev = tanhf(A_emb[act * D_ + d]);
    const float g = gp[d];
    const size_t base = ((size_t)b * S_ + 2 * t) * D_ + d;
    x[base]      = f2b(sev + g + pos_emb[(2 * t) * D_ + d]);
    x[base + D_] = f2b(aev + g + pos_emb[(2 * t + 1) * D_ + d]);
  }
}

// ---------------- layernorm: bf16 x row -> bf16 h row
__global__ __launch_bounds__(256) void ln_kernel(const short* __restrict__ x,
                                                 const float* __restrict__ gg,
                                                 const float* __restrict__ bb,
                                                 short* __restrict__ out) {
  __shared__ float red[4];
  const int row = blockIdx.x, tid = threadIdx.x;
  const short* xr = x + (size_t)row * D_;
  f32x4 v = {0.f, 0.f, 0.f, 0.f};
  if (tid < 192) {
    const s16x4 xv = *(const s16x4*)&xr[tid * 4];
    v.x = b2f(xv.x); v.y = b2f(xv.y); v.z = b2f(xv.z); v.w = b2f(xv.w);
  }
  float s = v.x + v.y + v.z + v.w;
  #pragma unroll
  for (int o = 32; o > 0; o >>= 1) s += __shfl_xor(s, o);
  if ((tid & 63) == 0) red[tid >> 6] = s;
  __syncthreads();
  const float mean = (red[0] + red[1] + red[2] + red[3]) * (1.0f / D_);
  __syncthreads();
  const f32x4 d = {v.x - mean, v.y - mean, v.z - mean, v.w - mean};
  float s2 = (tid < 192) ? (d.x * d.x + d.y * d.y + d.z * d.z + d.w * d.w) : 0.f;
  #pragma unroll
  for (int o = 32; o > 0; o >>= 1) s2 += __shfl_xor(s2, o);
  if ((tid & 63) == 0) red[tid >> 6] = s2;
  __syncthreads();
  const float inv = rsqrtf((red[0] + red[1] + red[2] + red[3]) * (1.0f / D_) + 1e-5f);
  if (tid < 192) {
    const f32x4 g = *(const f32x4*)&gg[tid * 4];
    const f32x4 b = *(const f32x4*)&bb[tid * 4];
    s16x4 o4;
    o4.x = f2b(d.x * inv * g.x + b.x);
    o4.y = f2b(d.y * inv * g.y + b.y);
    o4.z = f2b(d.z * inv * g.z + b.z);
    o4.w = f2b(d.w * inv * g.w + b.w);
    *(s16x4*)&out[(size_t)row * D_ + tid * 4] = o4;
  }
}

// ---------------- split-K2 reduce (bf16 partials, bf16 x) + bias + residual + LN
template <int MODE>
__global__ __launch_bounds__(256) void reduce2_kernel(
    const short* __restrict__ P, const float* __restrict__ bias,
    short* __restrict__ x, const float* __restrict__ gg,
    const float* __restrict__ bb, short* __restrict__ h,
    float* __restrict__ out) {
  __shared__ float red[4];
  const int row = (MODE == 2) ? (blockIdx.x * 2) : blockIdx.x;
  const int tid = threadIdx.x;
  const short* p0 = P + (size_t)row * D_;
  const short* p1 = P + (size_t)M_ * D_ + (size_t)row * D_;
  short* xr = x + (size_t)row * D_;
  f32x4 v = {0.f, 0.f, 0.f, 0.f};
  if (tid < 192) {
    const s16x4 a = *(const s16x4*)&xr[tid * 4];
    const s16x4 q0 = *(const s16x4*)&p0[tid * 4];
    const s16x4 q1 = *(const s16x4*)&p1[tid * 4];
    const f32x4 bv = *(const f32x4*)&bias[tid * 4];
    v.x = b2f(a.x) + b2f(q0.x) + b2f(q1.x) + bv.x;
    v.y = b2f(a.y) + b2f(q0.y) + b2f(q1.y) + bv.y;
    v.z = b2f(a.z) + b2f(q0.z) + b2f(q1.z) + bv.z;
    v.w = b2f(a.w) + b2f(q0.w) + b2f(q1.w) + bv.w;
    if (MODE == 1) {
      s16x4 xo;
      xo.x = f2b(v.x); xo.y = f2b(v.y); xo.z = f2b(v.z); xo.w = f2b(v.w);
      *(s16x4*)&xr[tid * 4] = xo;
    }
  }
  float s = v.x + v.y + v.z + v.w;
  #pragma unroll
  for (int o = 32; o > 0; o >>= 1) s += __shfl_xor(s, o);
  if ((tid & 63) == 0) red[tid >> 6] = s;
  __syncthreads();
  const float mean = (red[0] + red[1] + red[2] + red[3]) * (1.0f / D_);
  __syncthreads();
  const f32x4 d = {v.x - mean, v.y - mean, v.z - mean, v.w - mean};
  float s2 = (tid < 192) ? (d.x * d.x + d.y * d.y + d.z * d.z + d.w * d.w) : 0.f;
  #pragma unroll
  for (int o = 32; o > 0; o >>= 1) s2 += __shfl_xor(s2, o);
  if ((tid & 63) == 0) red[tid >> 6] = s2;
  __syncthreads();
  const float inv = rsqrtf((red[0] + red[1] + red[2] + red[3]) * (1.0f / D_) + 1e-5f);
  if (tid < 192) {
    const f32x4 g = *(const f32x4*)&gg[tid * 4];
    const f32x4 b = *(const f32x4*)&bb[tid * 4];
    if (MODE == 1) {
      s16x4 o4;
      o4.x = f2b(d.x * inv * g.x + b.x);
      o4.y = f2b(d.y * inv * g.y + b.y);
      o4.z = f2b(d.z * inv * g.z + b.z);
      o4.w = f2b(d.w * inv * g.w + b.w);
      *(s16x4*)&h[(size_t)row * D_ + tid * 4] = o4;
    } else {
      const int bb2 = row >> 10, t = (row & 1023) >> 1;
      f32x4 o4;
      o4.x = d.x * inv * g.x + b.x;
      o4.y = d.y * inv * g.y + b.y;
      o4.z = d.z * inv * g.z + b.z;
      o4.w = d.w * inv * g.w + b.w;
      *(f32x4*)&out[((size_t)bb2 * T_ + t) * D_ + tid * 4] = o4;
    }
  }
}

// ---------------- 128x128 main loop, BK=64, chunk-XOR swizzle (embed GEMM)
__device__ __forceinline__ void mainloop128(const short* __restrict__ gA,
                                            const short* __restrict__ gB,
                                            int K, int kIters,
                                            short* As, short* Bs,
                                            int wave, int l15, int lq, int wr, int wc,
                                            f32x4 (&acc)[4][4]) {
  auto STAGE = [&](int kt, int buf) {
    const short* a = gA + kt * 64;
    const short* b = gB + kt * 64;
    short* la = As + buf * 8192 + wave * 512;
    short* lb = Bs + buf * 8192 + wave * 512;
    #pragma unroll
    for (int j = 0; j < 4; ++j) {
      __builtin_amdgcn_global_load_lds(GBL_CAST(a + (size_t)(j * 32) * K), LDS_CAST(la + j * 2048), 16, 0, 0);
      __builtin_amdgcn_global_load_lds(GBL_CAST(b + (size_t)(j * 32) * K), LDS_CAST(lb + j * 2048), 16, 0, 0);
    }
  };
  STAGE(0, 0);
  __syncthreads();
  int cur = 0;
  const int swz = l15 & 7;
  for (int kt = 0; kt < kIters; ++kt) {
    if (kt + 1 < kIters) STAGE(kt + 1, cur ^ 1);
    const short* Ab = As + cur * 8192;
    const short* Bb = Bs + cur * 8192;
    #pragma unroll
    for (int s = 0; s < 2; ++s) {
      const int ck = ((s * 4 + lq) ^ swz) * 8;
      b16x8 af[4], bfr[4];
      #pragma unroll
      for (int i = 0; i < 4; ++i)
        af[i] = *(const b16x8*)&Ab[(wr * 64 + i * 16 + l15) * 64 + ck];
      #pragma unroll
      for (int j = 0; j < 4; ++j)
        bfr[j] = *(const b16x8*)&Bb[(wc * 64 + j * 16 + l15) * 64 + ck];
      __builtin_amdgcn_s_setprio(1);
      #pragma unroll
      for (int i = 0; i < 4; ++i)
        #pragma unroll
        for (int j = 0; j < 4; ++j)
          acc[i][j] = __builtin_amdgcn_mfma_f32_16x16x32_bf16(af[i], bfr[j], acc[i][j], 0, 0, 0);
      __builtin_amdgcn_s_setprio(0);
    }
    __syncthreads();
    cur ^= 1;
  }
}

// ---------------- GEMM 128x128 (embed path): EPI 4: tanh->bf16
template <int EPI>
__global__ __launch_bounds__(256) void gemm_bf16(const short* __restrict__ A,
                                                 const short* __restrict__ Bt,
                                                 const float* __restrict__ bias,
                                                 short* __restrict__ Cb,
                                                 int M, int N, int K) {
  __shared__ __align__(16) short As[16384];
  __shared__ __align__(16) short Bs[16384];
  const int tid = threadIdx.x;
  const int wave = tid >> 6, lane = tid & 63;
  const int l15 = lane & 15, lq = lane >> 4;
  const int wr = wave >> 1, wc = wave & 1;
  const int row0 = blockIdx.x * 128, col0 = blockIdx.y * 128;
  const int srow = wave * 8 + (lane >> 3);
  const int acs = ((lane & 7) ^ ((lane >> 3) & 7)) * 8;

  const short* gA = A + (size_t)(row0 + srow) * K + acs;
  const short* gB = Bt + (size_t)(col0 + srow) * K + acs;
  f32x4 acc[4][4] = {};
  mainloop128(gA, gB, K, K / 64, As, Bs, wave, l15, lq, wr, wc, acc);

  #pragma unroll
  for (int i = 0; i < 4; ++i) {
    #pragma unroll
    for (int j = 0; j < 4; ++j) {
      const int col = col0 + wc * 64 + j * 16 + l15;
      const float bv = bias[col];
      #pragma unroll
      for (int r = 0; r < 4; ++r) {
        const int row = row0 + wr * 64 + i * 16 + lq * 4 + r;
        const float v = acc[i][j][r] + bv;
        const size_t idx = (size_t)row * N + col;
        if (EPI == 1) Cb[idx] = f2b(gelu_f(v));
        else          Cb[idx] = f2b(tanh_f(v));
      }
    }
  }
}

// ================ 192-wide GEMM, BM x 192 tile, BK=64, chunk-XOR swizzle
// EPI 1: gelu->bf16 (Cb); EPI 2: bf16 partial (Cb + z*M*N); EPI 3: bf16 residual += (Xres)
template <int BM, int EPI>
__global__ __launch_bounds__(256) void gemm192(const short* __restrict__ A,
                                               const short* __restrict__ Bt,
                                               const float* __restrict__ bias,
                                               short* __restrict__ Cb,
                                               short* __restrict__ Xres,
                                               int M, int N, int K, int KC) {
  constexpr int AHALF = BM * 64;
  __shared__ __align__(16) short As[2 * AHALF];
  __shared__ __align__(16) short Bs[24576];
  const int tid = threadIdx.x;
  const int wave = tid >> 6, lane = tid & 63;
  const int l15 = lane & 15, lq = lane >> 4;
  const int wr = wave >> 1, wc = wave & 1;
  const int row0 = blockIdx.x * BM, col0 = blockIdx.y * 192;
  const int k0 = blockIdx.z * KC;
  const int srow = wave * 8 + (lane >> 3);
  const int acs = ((lane & 7) ^ ((lane >> 3) & 7)) * 8;

  const short* gA = A + (size_t)(row0 + srow) * K + acs + k0;
  const short* gB = Bt + (size_t)(col0 + srow) * K + acs + k0;

  auto STAGE = [&](int kt, int buf) {
    const short* a = gA + kt * 64;
    const short* b = gB + kt * 64;
    short* la = As + buf * AHALF + wave * 512;
    short* lb = Bs + buf * 12288 + wave * 512;
    #pragma unroll
    for (int j = 0; j < BM / 32; ++j)
      __builtin_amdgcn_global_load_lds(GBL_CAST(a + (size_t)(j * 32) * K), LDS_CAST(la + j * 2048), 16, 0, 0);
    #pragma unroll
    for (int j = 0; j < 6; ++j)
      __builtin_amdgcn_global_load_lds(GBL_CAST(b + (size_t)(j * 32) * K), LDS_CAST(lb + j * 2048), 16, 0, 0);
  };

  constexpr int MI = BM / 32;
  f32x4 acc[MI][6] = {};
  const int kIters = KC / 64;
  STAGE(0, 0);
  __syncthreads();
  int cur = 0;
  const int swz = l15 & 7;
  for (int kt = 0; kt < kIters; ++kt) {
    if (kt + 1 < kIters) STAGE(kt + 1, cur ^ 1);
    const short* Ab = As + cur * AHALF;
    const short* Bb = Bs + cur * 12288;
    #pragma unroll
    for (int s = 0; s < 2; ++s) {
      const int ck = ((s * 4 + lq) ^ swz) * 8;
      b16x8 af[MI], bfr[6];
      #pragma unroll
      for (int i = 0; i < MI; ++i)
        af[i] = *(const b16x8*)&Ab[(wr * (BM / 2) + i * 16 + l15) * 64 + ck];
      #pragma unroll
      for (int j = 0; j < 6; ++j)
        bfr[j] = *(const b16x8*)&Bb[(wc * 96 + j * 16 + l15) * 64 + ck];
      __builtin_amdgcn_s_setprio(1);
      #pragma unroll
      for (int i = 0; i < MI; ++i)
        #pragma unroll
        for (int j = 0; j < 6; ++j)
          acc[i][j] = __builtin_amdgcn_mfma_f32_16x16x32_bf16(af[i], bfr[j], acc[i][j], 0, 0, 0);
      __builtin_amdgcn_s_setprio(0);
    }
    __syncthreads();
    cur ^= 1;
  }

  #pragma unroll
  for (int i = 0; i < MI; ++i) {
    #pragma unroll
    for (int j = 0; j < 6; ++j) {
      const int col = col0 + wc * 96 + j * 16 + l15;
      #pragma unroll
      for (int r = 0; r < 4; ++r) {
        const int row = row0 + wr * (BM / 2) + i * 16 + lq * 4 + r;
        if (EPI == 1) {
          Cb[(size_t)row * N + col] = f2b(gelu_f(acc[i][j][r] + bias[col]));
        } else if (EPI == 2) {
          (Cb + (size_t)blockIdx.z * M * N)[(size_t)row * N + col] = f2b(acc[i][j][r]);
        } else {
          short* xp = &Xres[(size_t)row * N + col];
          *xp = f2b(b2f(*xp) + acc[i][j][r] + bias[col]);
        }
      }
    }
  }
}

// ---------------- fused QKV GEMM, 128x192 tile, BK=64 (R15-verified)
__global__ __launch_bounds__(256) void gemm_qkv(const short* __restrict__ A,
                                                const short* __restrict__ Bt,
                                                const float* __restrict__ bq,
                                                const float* __restrict__ bk,
                                                const float* __restrict__ bv,
                                                short* __restrict__ Cb, int K) {
  __shared__ __align__(16) short As[16384];
  __shared__ __align__(16) short Bs[24576];
  const int tid = threadIdx.x;
  const int wave = tid >> 6, lane = tid & 63;
  const int l15 = lane & 15, lq = lane >> 4;
  const int wr = wave >> 1, wc = wave & 1;
  const int row0 = blockIdx.x * 128, col0 = blockIdx.y * 192;
  const int seg = col0 / D_;
  const float* bias = (seg == 0) ? bq : (seg == 1) ? bk : bv;
  const float scale = (seg == 0) ? 0.125f : 1.0f;
  const int srow = wave * 8 + (lane >> 3);
  const int acs = ((lane & 7) ^ ((lane >> 3) & 7)) * 8;

  const short* gA = A + (size_t)(row0 + srow) * K + acs;
  const short* gB = Bt + (size_t)(col0 + srow) * K + acs;

  auto STAGE = [&](int kt, int buf) {
    const short* a = gA + kt * 64;
    const short* b = gB + kt * 64;
    short* la = As + buf * 8192 + wave * 512;
    short* lb = Bs + buf * 12288 + wave * 512;
    #pragma unroll
    for (int j = 0; j < 4; ++j)
      __builtin_amdgcn_global_load_lds(GBL_CAST(a + (size_t)(j * 32) * K), LDS_CAST(la + j * 2048), 16, 0, 0);
    #pragma unroll
    for (int j = 0; j < 6; ++j)
      __builtin_amdgcn_global_load_lds(GBL_CAST(b + (size_t)(j * 32) * K), LDS_CAST(lb + j * 2048), 16, 0, 0);
  };

  f32x4 acc[4][6] = {};
  const int kIters = K / 64;
  STAGE(0, 0);
  __syncthreads();
  int cur = 0;
  const int swz = l15 & 7;
  for (int kt = 0; kt < kIters; ++kt) {
    if (kt + 1 < kIters) STAGE(kt + 1, cur ^ 1);
    const short* Ab = As + cur * 8192;
    const short* Bb = Bs + cur * 12288;
    #pragma unroll
    for (int s = 0; s < 2; ++s) {
      const int ck = ((s * 4 + lq) ^ swz) * 8;
      b16x8 af[4], bfr[6];
      #pragma unroll
      for (int i = 0; i < 4; ++i)
        af[i] = *(const b16x8*)&Ab[(wr * 64 + i * 16 + l15) * 64 + ck];
      #pragma unroll
      for (int j = 0; j < 6; ++j)
        bfr[j] = *(const b16x8*)&Bb[(wc * 96 + j * 16 + l15) * 64 + ck];
      __builtin_amdgcn_s_setprio(1);
      #pragma unroll
      for (int i = 0; i < 4; ++i)
        #pragma unroll
        for (int j = 0; j < 6; ++j)
          acc[i][j] = __builtin_amdgcn_mfma_f32_16x16x32_bf16(af[i], bfr[j], acc[i][j], 0, 0, 0);
      __builtin_amdgcn_s_setprio(0);
    }
    __syncthreads();
    cur ^= 1;
  }

  #pragma unroll
  for (int i = 0; i < 4; ++i) {
    #pragma unroll
    for (int j = 0; j < 6; ++j) {
      const int col = col0 + wc * 96 + j * 16 + l15;
      const float bv = bias[col - seg * D_];
      #pragma unroll
      for (int r = 0; r < 4; ++r) {
        const int row = row0 + wr * 64 + i * 16 + lq * 4 + r;
        Cb[(size_t)row * QKVD + col] = f2b((acc[i][j][r] + bv) * scale);
      }
    }
  }
}

// ---------------- flash attention, balanced pairing, FIXED-MAX softmax, T14 split
__global__ __launch_bounds__(256) void attn_kernel(const short* __restrict__ qkv,
                                                   short* __restrict__ yb) {
  __shared__ __align__(16) short Ks[2][4096];
  __shared__ __align__(16) short Vt[2][64 * 72];
  __shared__ __align__(16) short Ps[4][16 * 88];

  const int bh = blockIdx.x, pair = blockIdx.y;
  const int h = bh % H_, b = bh / H_;
  const int tid = threadIdx.x, wave = tid >> 6, lane = tid & 63;
  const int l15 = lane & 15, lq = lane >> 4;

  const int r0 = tid >> 3, c0 = tid & 7;
  const int r1 = (tid + 256) >> 3;
  const int vkey = tid >> 2, vdhg = tid & 3;

  for (int t2 = 0; t2 < 2; ++t2) {
    const int qt = t2 ? (15 - pair) : pair;
    const int nkt = qt + 1;
    const int qrow0 = qt * 64 + wave * 16;

    const short* qp = qkv + (size_t)(b * S_ + qrow0 + l15) * QKVD + h * 64 + lq * 8;
    const b16x8 qf0 = *(const b16x8*)qp;
    const b16x8 qf1 = *(const b16x8*)(qp + 32);

    f32x4 o[4] = {};
    float lacc[4] = {0.f, 0.f, 0.f, 0.f};

    auto issueK = [&](int kt, int s) {
      const int kbase = kt * 64;
      const short* gk0 = qkv + (size_t)(b * S_ + kbase + r0) * QKVD + D_ + h * 64 + ((c0 ^ (r0 & 7)) * 8);
      __builtin_amdgcn_global_load_lds(GBL_CAST(gk0), LDS_CAST(&Ks[s][wave * 512]), 16, 0, 0);
      const short* gk1 = qkv + (size_t)(b * S_ + kbase + r1) * QKVD + D_ + h * 64 + ((c0 ^ (r1 & 7)) * 8);
      __builtin_amdgcn_global_load_lds(GBL_CAST(gk1), LDS_CAST(&Ks[s][2048 + wave * 512]), 16, 0, 0);
    };
    auto loadV = [&](int kt, b16x8& v0, b16x8& v1) {
      const short* gv = qkv + (size_t)(b * S_ + kt * 64 + vkey) * QKVD + 2 * D_ + h * 64 + vdhg * 16;
      v0 = *(const b16x8*)gv;
      v1 = *(const b16x8*)(gv + 8);
    };
    auto writeV = [&](int s, const b16x8& v0, const b16x8& v1) {
      #pragma unroll
      for (int e = 0; e < 8; ++e) Vt[s][(vdhg * 16 + e) * 72 + vkey] = v0[e];
      #pragma unroll
      for (int e = 0; e < 8; ++e) Vt[s][(vdhg * 16 + 8 + e) * 72 + vkey] = v1[e];
    };

    {
      b16x8 pv0, pv1;
      issueK(0, 0);
      loadV(0, pv0, pv1);
      writeV(0, pv0, pv1);
    }
    __syncthreads();

    for (int kt = 0; kt < nkt; ++kt) {
      const int cur = kt & 1;
      const bool have_next = (kt + 1 < nkt);
      b16x8 nv0, nv1;
      if (have_next) {
        issueK(kt + 1, cur ^ 1);
        loadV(kt + 1, nv0, nv1);
      }
      const int kbase = kt * 64;
      const bool needmask = (kt == qt);

      f32x4 s4[4];
      #pragma unroll
      for (int j = 0; j < 4; ++j) {
        const int krow = j * 16 + l15;
        const b16x8 kf0 = *(const b16x8*)&Ks[cur][krow * 64 + ((lq ^ (krow & 7)) * 8)];
        const b16x8 kf1 = *(const b16x8*)&Ks[cur][krow * 64 + (((4 + lq) ^ (krow & 7)) * 8)];
        f32x4 z = {};
        z = __builtin_amdgcn_mfma_f32_16x16x32_bf16(qf0, kf0, z, 0, 0, 0);
        s4[j] = __builtin_amdgcn_mfma_f32_16x16x32_bf16(qf1, kf1, z, 0, 0, 0);
      }

      #pragma unroll
      for (int r = 0; r < 4; ++r) {
        const int q = qrow0 + lq * 4 + r;
        float psum = 0.f;
        #pragma unroll
        for (int j = 0; j < 4; ++j) {
          float pp = __expf(s4[j][r]);
          if (needmask && (kbase + j * 16 + l15 > q)) pp = 0.f;
          psum += pp;
          Ps[wave][(lq * 4 + r) * 88 + j * 16 + l15] = f2b(pp);
        }
        lacc[r] += psum;
      }

      if (have_next) writeV(cur ^ 1, nv0, nv1);

      #pragma unroll
      for (int c = 0; c < 2; ++c) {
        const b16x8 pf = *(const b16x8*)&Ps[wave][l15 * 88 + c * 32 + lq * 8];
        #pragma unroll
        for (int jn = 0; jn < 4; ++jn) {
          const b16x8 vf = *(const b16x8*)&Vt[cur][(jn * 16 + l15) * 72 + c * 32 + lq * 8];
          o[jn] = __builtin_amdgcn_mfma_f32_16x16x32_bf16(pf, vf, o[jn], 0, 0, 0);
        }
      }
      __syncthreads();
    }

    #pragma unroll
    for (int r = 0; r < 4; ++r) {
      #pragma unroll
      for (int ofs = 1; ofs < 16; ofs <<= 1) lacc[r] += __shfl_xor(lacc[r], ofs);
      lacc[r] = 1.0f / lacc[r];
    }

    #pragma unroll
    for (int jn = 0; jn < 4; ++jn) {
      #pragma unroll
      for (int r = 0; r < 4; ++r) {
        const int q = qrow0 + lq * 4 + r;
        const int dh = jn * 16 + l15;
        yb[(size_t)(b * S_ + q) * D_ + h * 64 + dh] = f2b(o[jn][r] * lacc[r]);
      }
    }
  }
}

// ---------------- host-side orchestration
extern "C" void kernel_launch(void* const* d_in, const int* in_sizes, int n_in,
                              void* d_out, int out_size, void* d_ws, size_t ws_size,
                              hipStream_t stream) {
  (void)in_sizes; (void)n_in; (void)out_size; (void)ws_size;
  const float* states    = (const float*)d_in[0];
  const int*   actions   = (const int*)d_in[1];
  const int*   timesteps = (const int*)d_in[2];
  const float* W_s       = (const float*)d_in[3];
  const float* b_s       = (const float*)d_in[4];
  const float* A_emb     = (const float*)d_in[5];
  const float* pos_emb   = (const float*)d_in[6];
  const float* gpos_emb  = (const float*)d_in[7];
  const float* ln1_g     = (const float*)d_in[8];
  const float* ln1_b     = (const float*)d_in[9];
  const float* Wq        = (const float*)d_in[10];
  const float* bq        = (const float*)d_in[11];
  const float* Wk        = (const float*)d_in[12];
  const float* bk        = (const float*)d_in[13];
  const float* Wv        = (const float*)d_in[14];
  const float* bv        = (const float*)d_in[15];
  const float* Wp        = (const float*)d_in[16];
  const float* bp        = (const float*)d_in[17];
  const float* ln2_g     = (const float*)d_in[18];
  const float* ln2_b     = (const float*)d_in[19];
  const float* W1        = (const float*)d_in[20];
  const float* b1        = (const float*)d_in[21];
  const float* W2        = (const float*)d_in[22];
  const float* b2        = (const float*)d_in[23];
  const float* lnf_g     = (const float*)d_in[24];
  const float* lnf_b     = (const float*)d_in[25];
  float* out = (float*)d_out;

  char* p = (char*)d_ws;
  short* x    = (short*)p; p += (size_t)M_ * D_ * 2;
  short* h    = (short*)p; p += (size_t)M_ * D_ * 2;
  short* qkv  = (short*)p; p += (size_t)M_ * QKVD * 2;
  short* y    = (short*)p; p += (size_t)M_ * D_ * 2;
  short* gbf  = (short*)p; p += (size_t)M_ * DFF_ * 2;
  short* wqkvt= (short*)p; p += (size_t)QKVD * D_ * 2;
  short* wpt  = (short*)p; p += (size_t)D_ * D_ * 2;
  short* w1t  = (short*)p; p += (size_t)D_ * DFF_ * 2;
  short* w2t  = (short*)p; p += (size_t)D_ * DFF_ * 2;
  // split-K bf16 partial buffer [2][M][D] aliases qkv+y (dead when FFN2 runs)
  short* Pbuf = qkv;
  // transient (pre-layer) aliases
  short* sbf  = qkv;                       // [4096][128] bf16
  short* wst  = qkv + (size_t)4096 * 128;  // [768][128] bf16
  short* se   = gbf;                       // [4096][768] bf16

  // ---- embedding path
  cvt_kernel<<<(B_ * T_ * 128) / 1024, 256, 0, stream>>>(states, sbf, B_ * T_ * 128);
  trconv_kernel<<<dim3(4, 24), 256, 0, stream>>>(W_s, wst, 128, D_);
  gemm_bf16<4><<<dim3(32, 6), 256, 0, stream>>>(sbf, wst, b_s, se, 4096, D_, 128);
  embed2_kernel<<<B_ * T_, 256, 0, stream>>>(se, actions, timesteps, A_emb, pos_emb, gpos_emb, x);
  ln_kernel<<<M_, 256, 0, stream>>>(x, ln1_g, ln1_b, h);

  for (int l = 0; l < L_; ++l) {
    trconv_layer<<<3456, 256, 0, stream>>>(
        Wq + (size_t)l * D_ * D_, Wk + (size_t)l * D_ * D_,
        Wv + (size_t)l * D_ * D_, Wp + (size_t)l * D_ * D_,
        W1 + (size_t)l * D_ * DFF_, W2 + (size_t)l * D_ * DFF_,
        wqkvt, wpt, w1t, w2t);

    gemm_qkv<<<dim3(M_ / 128, QKVD / 192), 256, 0, stream>>>(h, wqkvt, bq + l * D_, bk + l * D_, bv + l * D_, qkv, D_);
    attn_kernel<<<dim3(B_ * H_, 8), 256, 0, stream>>>(qkv, y);
    gemm192<64, 3><<<dim3(M_ / 64, D_ / 192), 256, 0, stream>>>(
        y, wpt, bp + l * D_, nullptr, x, M_, D_, D_, D_);
    ln_kernel<<<M_, 256, 0, stream>>>(x, ln2_g + l * D_, ln2_b + l * D_, h);
    gemm192<128, 1><<<dim3(M_ / 128, DFF_ / 192), 256, 0, stream>>>(
        h, w1t, b1 + l * DFF_, gbf, nullptr, M_, DFF_, D_, D_);
    gemm192<128, 2><<<dim3(M_ / 128, D_ / 192, 2), 256, 0, stream>>>(
        gbf, w2t, nullptr, Pbuf, nullptr, M_, D_, DFF_, DFF_ / 2);
    if (l < L_ - 1) {
      reduce2_kernel<1><<<M_, 256, 0, stream>>>(Pbuf, b2 + l * D_, x,
                                                ln1_g + (l + 1) * D_, ln1_b + (l + 1) * D_, h, nullptr);
    } else {
      reduce2_kernel<2><<<M_ / 2, 256, 0, stream>>>(Pbuf, b2 + l * D_, x, lnf_g, lnf_b, nullptr, out);
    }
  }
}